// Round 1
// baseline (1246.066 us; speedup 1.0000x reference)
//
#include <hip/hip_runtime.h>
#include <math.h>

#define TDIM 16384
#define DDIM 1024
#define CDIM 256
#define KDIM 8192
#define KSPLIT 4

// ---- workspace layout (float offsets) ----
static const size_t OFF_WIN  = 0;                                   // 256x1024
static const size_t OFF_WOUT = OFF_WIN  + (size_t)CDIM * DDIM;      // 1024x256
static const size_t OFF_CBU  = OFF_WOUT + (size_t)DDIM * CDIM;      // 8192x256
static const size_t OFF_C2   = OFF_CBU  + (size_t)KDIM * CDIM;      // 8192
static const size_t OFF_ZE   = OFF_C2   + (size_t)KDIM;             // 256x16384
static const size_t OFF_INV  = OFF_ZE   + (size_t)CDIM * TDIM;      // 16384
static const size_t OFF_QT   = OFF_INV  + (size_t)TDIM;             // 16384x256
static const size_t OFF_PV   = OFF_QT   + (size_t)TDIM * CDIM;      // 4x16384
static const size_t OFF_PI   = OFF_PV   + (size_t)KSPLIT * TDIM;    // 4x16384 (int)
static const size_t OFF_IDX  = OFF_PI   + (size_t)KSPLIT * TDIM;    // 16384 (int)

// ---------------------------------------------------------------------------
// Row-wise L2 normalize: w[row] = (g?g[row]:1) * v[row] / norm(v[row])
// optional clip(norm, 1e-12); optional c2[row] = sum(w[row]^2) of ROUNDED w.
// ---------------------------------------------------------------------------
__global__ __launch_bounds__(256) void rownorm_kernel(
    const float* __restrict__ v, const float* __restrict__ g,
    float* __restrict__ w, float* __restrict__ c2, int ncols, int clip) {
  __shared__ float red[256];
  int row = blockIdx.x;
  const float* vr = v + (size_t)row * ncols;
  float* wr = w + (size_t)row * ncols;
  float s = 0.f;
  for (int j = threadIdx.x; j < ncols; j += 256) { float x = vr[j]; s += x * x; }
  red[threadIdx.x] = s;
  __syncthreads();
  for (int off = 128; off > 0; off >>= 1) {
    if (threadIdx.x < off) red[threadIdx.x] += red[threadIdx.x + off];
    __syncthreads();
  }
  float norm = sqrtf(red[0]);
  if (clip) norm = fmaxf(norm, 1e-12f);
  float scale = (g ? g[row] : 1.0f) / norm;
  float s2 = 0.f;
  for (int j = threadIdx.x; j < ncols; j += 256) {
    float y = vr[j] * scale;
    wr[j] = y;
    s2 += y * y;
  }
  if (c2) {
    __syncthreads();
    red[threadIdx.x] = s2;
    __syncthreads();
    for (int off = 128; off > 0; off >>= 1) {
      if (threadIdx.x < off) red[threadIdx.x] += red[threadIdx.x + off];
      __syncthreads();
    }
    if (threadIdx.x == 0) c2[row] = red[0];
  }
}

// ---------------------------------------------------------------------------
// in_proj: C(256 x 16384) = A(256x1024) @ B(1024x16384) + bias[m]
// BM=128 BN=64 BK=8, 256 thr, microtile 8x4
// ---------------------------------------------------------------------------
__global__ __launch_bounds__(256) void gemm_in_proj(
    const float* __restrict__ A, const float* __restrict__ B,
    const float* __restrict__ bias, float* __restrict__ C) {
  __shared__ float As[8][128];
  __shared__ float Bs[8][64];
  const int K = 1024, N = TDIM;
  int m0 = blockIdx.y * 128;
  int n0 = blockIdx.x * 64;
  int tid = threadIdx.x;
  int tm0 = (tid >> 4) * 8;
  int tn0 = (tid & 15) * 4;
  int a_r = tid >> 1, a_c = (tid & 1) * 4;
  int b_r = tid >> 5, b_c = (tid & 31) * 2;
  float acc[8][4] = {};
  for (int k0 = 0; k0 < K; k0 += 8) {
    float4 av = *(const float4*)&A[(size_t)(m0 + a_r) * K + k0 + a_c];
    float2 bv = *(const float2*)&B[(size_t)(k0 + b_r) * N + n0 + b_c];
    __syncthreads();
    As[a_c + 0][a_r] = av.x; As[a_c + 1][a_r] = av.y;
    As[a_c + 2][a_r] = av.z; As[a_c + 3][a_r] = av.w;
    Bs[b_r][b_c] = bv.x; Bs[b_r][b_c + 1] = bv.y;
    __syncthreads();
#pragma unroll
    for (int kk = 0; kk < 8; kk++) {
      float a[8], b[4];
      *(float4*)&a[0] = *(const float4*)&As[kk][tm0];
      *(float4*)&a[4] = *(const float4*)&As[kk][tm0 + 4];
      *(float4*)&b[0] = *(const float4*)&Bs[kk][tn0];
#pragma unroll
      for (int i = 0; i < 8; i++)
#pragma unroll
        for (int j = 0; j < 4; j++) acc[i][j] += a[i] * b[j];
    }
  }
#pragma unroll
  for (int i = 0; i < 8; i++) {
    float bb = bias[m0 + tm0 + i];
    float4 o;
    o.x = acc[i][0] + bb; o.y = acc[i][1] + bb;
    o.z = acc[i][2] + bb; o.w = acc[i][3] + bb;
    *(float4*)&C[(size_t)(m0 + tm0 + i) * N + n0 + tn0] = o;
  }
}

// ---------------------------------------------------------------------------
// column norms of z_e (CD x T): inv[t] = 1/clip(||z_e[:,t]||, 1e-12)
// ---------------------------------------------------------------------------
__global__ __launch_bounds__(256) void colnorm_kernel(
    const float* __restrict__ ze, float* __restrict__ inv) {
  __shared__ float red[4][64];
  int tl = threadIdx.x & 63, part = threadIdx.x >> 6;
  int t = blockIdx.x * 64 + tl;
  float s = 0.f;
  for (int c = part * 64; c < part * 64 + 64; c++) {
    float x = ze[(size_t)c * TDIM + t];
    s += x * x;
  }
  red[part][tl] = s;
  __syncthreads();
  if (part == 0) {
    float tot = red[0][tl] + red[1][tl] + red[2][tl] + red[3][tl];
    inv[t] = 1.0f / fmaxf(sqrtf(tot), 1e-12f);
  }
}

// ---------------------------------------------------------------------------
// dist + argmin: for t-tile (128) x k-range (KDIM/KSPLIT), running argmin of
//   s = c2[k] - 2 * dot(enc[:,t], cbu[k]),  enc = z_e[:,t] * inv[t]
// A^T layout = z_e (c-major), B^T layout = cbu (k-major). 8x8 microtile.
// ---------------------------------------------------------------------------
__global__ __launch_bounds__(256) void dist_argmin(
    const float* __restrict__ ze, const float* __restrict__ inv,
    const float* __restrict__ cbu, const float* __restrict__ c2,
    float* __restrict__ pv, int* __restrict__ pi) {
  __shared__ float As[8][128];
  __shared__ float Bs[8][128];
  __shared__ float rv[128 * 17];
  __shared__ int   ri[128 * 17];
  int t0 = blockIdx.x * 128;
  int ks = blockIdx.y;
  int kbeg = ks * (KDIM / KSPLIT);
  int tid = threadIdx.x;
  int tm0 = (tid >> 4) * 8, tn0 = (tid & 15) * 8;
  int ar = tid >> 5, ac4 = (tid & 31) * 4;   // A tile: [8 c][128 t]
  int br = tid >> 1, bc4 = (tid & 1) * 4;    // B tile: [128 k][8 c]
  float bv[8]; int bi[8];
#pragma unroll
  for (int i = 0; i < 8; i++) { bv[i] = INFINITY; bi[i] = 0x7fffffff; }

  for (int kc = 0; kc < KDIM / KSPLIT; kc += 128) {
    int k0 = kbeg + kc;
    float acc[8][8] = {};
    for (int c0 = 0; c0 < CDIM; c0 += 8) {
      float4 av = *(const float4*)&ze[(size_t)(c0 + ar) * TDIM + t0 + ac4];
      float4 iv = *(const float4*)&inv[t0 + ac4];
      float4 bw = *(const float4*)&cbu[(size_t)(k0 + br) * CDIM + c0 + bc4];
      __syncthreads();
      As[ar][ac4 + 0] = av.x * iv.x; As[ar][ac4 + 1] = av.y * iv.y;
      As[ar][ac4 + 2] = av.z * iv.z; As[ar][ac4 + 3] = av.w * iv.w;
      Bs[bc4 + 0][br] = bw.x; Bs[bc4 + 1][br] = bw.y;
      Bs[bc4 + 2][br] = bw.z; Bs[bc4 + 3][br] = bw.w;
      __syncthreads();
#pragma unroll
      for (int kk = 0; kk < 8; kk++) {
        float a[8], b[8];
        *(float4*)&a[0] = *(const float4*)&As[kk][tm0];
        *(float4*)&a[4] = *(const float4*)&As[kk][tm0 + 4];
        *(float4*)&b[0] = *(const float4*)&Bs[kk][tn0];
        *(float4*)&b[4] = *(const float4*)&Bs[kk][tn0 + 4];
#pragma unroll
        for (int i = 0; i < 8; i++)
#pragma unroll
          for (int j = 0; j < 8; j++) acc[i][j] += a[i] * b[j];
      }
    }
    float c2v[8];
    *(float4*)&c2v[0] = *(const float4*)&c2[k0 + tn0];
    *(float4*)&c2v[4] = *(const float4*)&c2[k0 + tn0 + 4];
#pragma unroll
    for (int i = 0; i < 8; i++)
#pragma unroll
      for (int j = 0; j < 8; j++) {
        float s = c2v[j] - 2.0f * acc[i][j];
        int kidx = k0 + tn0 + j;
        if (s < bv[i]) { bv[i] = s; bi[i] = kidx; }  // strict <: keep earliest k
      }
  }

  // cross-thread (tx) reduce per t row; tie-break: smaller k wins
  int tx = tid & 15;
#pragma unroll
  for (int i = 0; i < 8; i++) {
    rv[(tm0 + i) * 17 + tx] = bv[i];
    ri[(tm0 + i) * 17 + tx] = bi[i];
  }
  __syncthreads();
  if (tid < 128) {
    float fbv = INFINITY; int fbi = 0x7fffffff;
    for (int j = 0; j < 16; j++) {
      float v = rv[tid * 17 + j];
      int ii = ri[tid * 17 + j];
      if (v < fbv || (v == fbv && ii < fbi)) { fbv = v; fbi = ii; }
    }
    pv[(size_t)ks * TDIM + t0 + tid] = fbv;
    pi[(size_t)ks * TDIM + t0 + tid] = fbi;
  }
}

// ---------------------------------------------------------------------------
// merge k-splits; emit int idx (for gather) and float idx (output 1)
// ---------------------------------------------------------------------------
__global__ __launch_bounds__(256) void merge_argmin(
    const float* __restrict__ pv, const int* __restrict__ pi,
    int* __restrict__ idx, float* __restrict__ idxf) {
  int t = blockIdx.x * 256 + threadIdx.x;
  float bv = INFINITY; int bi = 0x7fffffff;
  for (int s = 0; s < KSPLIT; s++) {
    float v = pv[(size_t)s * TDIM + t];
    int ii = pi[(size_t)s * TDIM + t];
    if (v < bv || (v == bv && ii < bi)) { bv = v; bi = ii; }
  }
  idx[t] = bi;
  idxf[t] = (float)bi;
}

// ---------------------------------------------------------------------------
// STE gather: qT[t][c] = z_e[c][t] + (codebook[idx[t]][c] - z_e[c][t])
// (faithful fp32 rounding of the straight-through expression)
// ---------------------------------------------------------------------------
__global__ __launch_bounds__(256) void gather_qT(
    const int* __restrict__ idx, const float* __restrict__ cb,
    const float* __restrict__ ze, float* __restrict__ qT) {
  int t = blockIdx.x;
  int c = threadIdx.x;
  int k = idx[t];
  float cbv = cb[(size_t)k * CDIM + c];
  float zev = ze[(size_t)c * TDIM + t];
  qT[(size_t)t * CDIM + c] = zev + (cbv - zev);
}

// ---------------------------------------------------------------------------
// out_proj: C(1024 x 16384) = A(1024x256) @ qT(16384x256)^T + bias[m]
// BM=128 BN=128 BK=8, 256 thr, microtile 8x8
// ---------------------------------------------------------------------------
__global__ __launch_bounds__(256) void gemm_out_proj(
    const float* __restrict__ A, const float* __restrict__ Bt,
    const float* __restrict__ bias, float* __restrict__ C) {
  __shared__ float As[8][128];
  __shared__ float Bs[8][128];
  const int K = CDIM, N = TDIM;
  int m0 = blockIdx.y * 128;
  int n0 = blockIdx.x * 128;
  int tid = threadIdx.x;
  int tm0 = (tid >> 4) * 8, tn0 = (tid & 15) * 8;
  int a_r = tid >> 1, a_c = (tid & 1) * 4;
  float acc[8][8] = {};
  for (int k0 = 0; k0 < K; k0 += 8) {
    float4 av = *(const float4*)&A[(size_t)(m0 + a_r) * K + k0 + a_c];
    float4 bw = *(const float4*)&Bt[(size_t)(n0 + a_r) * K + k0 + a_c];
    __syncthreads();
    As[a_c + 0][a_r] = av.x; As[a_c + 1][a_r] = av.y;
    As[a_c + 2][a_r] = av.z; As[a_c + 3][a_r] = av.w;
    Bs[a_c + 0][a_r] = bw.x; Bs[a_c + 1][a_r] = bw.y;
    Bs[a_c + 2][a_r] = bw.z; Bs[a_c + 3][a_r] = bw.w;
    __syncthreads();
#pragma unroll
    for (int kk = 0; kk < 8; kk++) {
      float a[8], b[8];
      *(float4*)&a[0] = *(const float4*)&As[kk][tm0];
      *(float4*)&a[4] = *(const float4*)&As[kk][tm0 + 4];
      *(float4*)&b[0] = *(const float4*)&Bs[kk][tn0];
      *(float4*)&b[4] = *(const float4*)&Bs[kk][tn0 + 4];
#pragma unroll
      for (int i = 0; i < 8; i++)
#pragma unroll
        for (int j = 0; j < 8; j++) acc[i][j] += a[i] * b[j];
    }
  }
#pragma unroll
  for (int i = 0; i < 8; i++) {
    float bb = bias[m0 + tm0 + i];
    float4 o0, o1;
    o0.x = acc[i][0] + bb; o0.y = acc[i][1] + bb;
    o0.z = acc[i][2] + bb; o0.w = acc[i][3] + bb;
    o1.x = acc[i][4] + bb; o1.y = acc[i][5] + bb;
    o1.z = acc[i][6] + bb; o1.w = acc[i][7] + bb;
    *(float4*)&C[(size_t)(m0 + tm0 + i) * N + n0 + tn0] = o0;
    *(float4*)&C[(size_t)(m0 + tm0 + i) * N + n0 + tn0 + 4] = o1;
  }
}

extern "C" void kernel_launch(void* const* d_in, const int* in_sizes, int n_in,
                              void* d_out, int out_size, void* d_ws, size_t ws_size,
                              hipStream_t stream) {
  const float* z     = (const float*)d_in[0];
  const float* in_v  = (const float*)d_in[1];
  const float* in_g  = (const float*)d_in[2];
  const float* in_b  = (const float*)d_in[3];
  const float* out_v = (const float*)d_in[4];
  const float* out_g = (const float*)d_in[5];
  const float* out_b = (const float*)d_in[6];
  const float* cb    = (const float*)d_in[7];

  float* ws    = (float*)d_ws;
  float* W_in  = ws + OFF_WIN;
  float* W_out = ws + OFF_WOUT;
  float* cbu   = ws + OFF_CBU;
  float* c2    = ws + OFF_C2;
  float* z_e   = ws + OFF_ZE;
  float* invn  = ws + OFF_INV;
  float* qT    = ws + OFF_QT;
  float* pv    = ws + OFF_PV;
  int*   pi    = (int*)(ws + OFF_PI);
  int*   idxw  = (int*)(ws + OFF_IDX);

  float* outp = (float*)d_out;                 // (1024 x 16384) fp32
  float* idxf = outp + (size_t)DDIM * TDIM;    // indices as float32

  // weight-norm + codebook normalize
  rownorm_kernel<<<CDIM, 256, 0, stream>>>(in_v, in_g, W_in, nullptr, DDIM, 0);
  rownorm_kernel<<<DDIM, 256, 0, stream>>>(out_v, out_g, W_out, nullptr, CDIM, 0);
  rownorm_kernel<<<KDIM, 256, 0, stream>>>(cb, nullptr, cbu, c2, CDIM, 1);

  // z_e = W_in @ z + in_b
  gemm_in_proj<<<dim3(TDIM / 64, CDIM / 128), 256, 0, stream>>>(W_in, z, in_b, z_e);

  // inv column norms
  colnorm_kernel<<<TDIM / 64, 256, 0, stream>>>(z_e, invn);

  // nearest-codebook argmin (k-split x4)
  dist_argmin<<<dim3(TDIM / 128, KSPLIT), 256, 0, stream>>>(z_e, invn, cbu, c2, pv, pi);
  merge_argmin<<<TDIM / 256, 256, 0, stream>>>(pv, pi, idxw, idxf);

  // STE gather into (T x CD)
  gather_qT<<<TDIM, 256, 0, stream>>>(idxw, cb, z_e, qT);

  // out = W_out @ q' + out_b
  gemm_out_proj<<<dim3(TDIM / 128, DDIM / 128), 256, 0, stream>>>(W_out, qT, out_b, outp);
}